// Round 1
// baseline (485.893 us; speedup 1.0000x reference)
//
#include <hip/hip_runtime.h>

// Problem constants (from reference setup_inputs)
constexpr int B = 2, C = 4, D = 128, H = 160, W = 160;
constexpr int N = D * H * W;          // 3,276,800 spatial positions per batch

__global__ __launch_bounds__(256) void warp3d_kernel(
    const float* __restrict__ src,    // [B, C, D, H, W]
    const float* __restrict__ flow,   // [B, 3, D, H, W]
    float* __restrict__ out)          // [B, C, D, H, W]
{
    int tid = blockIdx.x * blockDim.x + threadIdx.x;
    if (tid >= B * N) return;

    int b = (tid >= N) ? 1 : 0;       // B == 2
    int s = tid - b * N;
    int x = s % W;
    int t = s / W;
    int y = t % H;
    int z = t / H;

    // flow is [B, 3, N]: channels z, y, x
    const float* fl = flow + b * 3 * N + s;
    float zc = (float)z + fl[0];
    float yc = (float)y + fl[N];
    float xc = (float)x + fl[2 * N];

    float z0f = floorf(zc), y0f = floorf(yc), x0f = floorf(xc);
    float wz = zc - z0f, wy = yc - y0f, wx = xc - x0f;
    float wz0 = 1.0f - wz, wy0 = 1.0f - wy, wx0 = 1.0f - wx;

    int z0 = (int)z0f, y0 = (int)y0f, x0 = (int)x0f;
    int z1 = z0 + 1, y1 = y0 + 1, x1 = x0 + 1;

    // zeros padding: validity per axis endpoint (unsigned trick: <0 wraps huge)
    bool vz0 = (unsigned)z0 < (unsigned)D, vz1 = (unsigned)z1 < (unsigned)D;
    bool vy0 = (unsigned)y0 < (unsigned)H, vy1 = (unsigned)y1 < (unsigned)H;
    bool vx0 = (unsigned)x0 < (unsigned)W, vx1 = (unsigned)x1 < (unsigned)W;

    // clamped coordinates for the address (invalid corners get weight 0)
    int z0c = min(max(z0, 0), D - 1), z1c = min(max(z1, 0), D - 1);
    int y0c = min(max(y0, 0), H - 1), y1c = min(max(y1, 0), H - 1);
    int x0c = min(max(x0, 0), W - 1), x1c = min(max(x1, 0), W - 1);

    float w000 = wz0 * wy0 * wx0 * (float)(vz0 && vy0 && vx0);
    float w001 = wz0 * wy0 * wx  * (float)(vz0 && vy0 && vx1);
    float w010 = wz0 * wy  * wx0 * (float)(vz0 && vy1 && vx0);
    float w011 = wz0 * wy  * wx  * (float)(vz0 && vy1 && vx1);
    float w100 = wz  * wy0 * wx0 * (float)(vz1 && vy0 && vx0);
    float w101 = wz  * wy0 * wx  * (float)(vz1 && vy0 && vx1);
    float w110 = wz  * wy  * wx0 * (float)(vz1 && vy1 && vx0);
    float w111 = wz  * wy  * wx  * (float)(vz1 && vy1 && vx1);

    int r00 = (z0c * H + y0c) * W;
    int r01 = (z0c * H + y1c) * W;
    int r10 = (z1c * H + y0c) * W;
    int r11 = (z1c * H + y1c) * W;
    int i000 = r00 + x0c, i001 = r00 + x1c;
    int i010 = r01 + x0c, i011 = r01 + x1c;
    int i100 = r10 + x0c, i101 = r10 + x1c;
    int i110 = r11 + x0c, i111 = r11 + x1c;

    const float* sb = src + b * C * N;
    float* ob = out + b * C * N + s;

    #pragma unroll
    for (int c = 0; c < C; ++c) {
        const float* sp = sb + c * N;
        float v = w000 * sp[i000] + w001 * sp[i001]
                + w010 * sp[i010] + w011 * sp[i011]
                + w100 * sp[i100] + w101 * sp[i101]
                + w110 * sp[i110] + w111 * sp[i111];
        ob[c * N] = v;
    }
}

extern "C" void kernel_launch(void* const* d_in, const int* in_sizes, int n_in,
                              void* d_out, int out_size, void* d_ws, size_t ws_size,
                              hipStream_t stream) {
    const float* src  = (const float*)d_in[0];
    const float* flow = (const float*)d_in[1];
    float* out = (float*)d_out;

    int total = B * N;                 // 6,553,600 threads
    int block = 256;
    int grid = (total + block - 1) / block;
    warp3d_kernel<<<grid, block, 0, stream>>>(src, flow, out);
}

// Round 2
// 275.777 us; speedup vs baseline: 1.7619x; 1.7619x over previous
//
#include <hip/hip_runtime.h>

// Problem constants (from reference setup_inputs)
constexpr int B = 2, C = 4, D = 128, H = 160, W = 160;
constexpr int N = D * H * W;          // 3,276,800 spatial positions per batch

// ---------------------------------------------------------------------------
// Pass 1: transpose src [B,C,D,H,W] -> src_t [B,D,H,W,C]  (float4 per voxel)
// Fully coalesced streaming: 4 plane-strided reads + 1 float4 write.
// ---------------------------------------------------------------------------
__global__ __launch_bounds__(256) void transpose_kernel(
    const float* __restrict__ src, float4* __restrict__ dst)
{
    int tid = blockIdx.x * blockDim.x + threadIdx.x;
    if (tid >= B * N) return;
    int b = (tid >= N) ? 1 : 0;       // B == 2
    int s = tid - b * N;
    const float* sb = src + b * C * N + s;
    float4 v;
    v.x = sb[0];
    v.y = sb[N];
    v.z = sb[2 * N];
    v.w = sb[3 * N];
    dst[tid] = v;                      // 16B aligned, coalesced
}

// ---------------------------------------------------------------------------
// Pass 2: trilinear warp using channel-interleaved src_t.
// 8 float4 gathers per thread (vs 32 scalar), nontemporal flow/out streaming
// so src_t stays resident in the 256MB L3.
// ---------------------------------------------------------------------------
__global__ __launch_bounds__(256) void warp3d_t_kernel(
    const float4* __restrict__ src_t,  // [B, N] float4
    const float* __restrict__ flow,    // [B, 3, N]
    float* __restrict__ out)           // [B, C, N]
{
    // bijective XCD swizzle: each XCD gets a contiguous chunk of the grid
    // (grid size is a multiple of 8 — asserted at launch)
    int chunk = (int)gridDim.x >> 3;
    int swz = ((int)blockIdx.x & 7) * chunk + ((int)blockIdx.x >> 3);
    int tid = swz * (int)blockDim.x + (int)threadIdx.x;
    if (tid >= B * N) return;

    int b = (tid >= N) ? 1 : 0;
    int s = tid - b * N;
    int x = s % W;
    int t = s / W;
    int y = t % H;
    int z = t / H;

    const float* fl = flow + b * 3 * N + s;
    float zc = (float)z + __builtin_nontemporal_load(fl);
    float yc = (float)y + __builtin_nontemporal_load(fl + N);
    float xc = (float)x + __builtin_nontemporal_load(fl + 2 * N);

    float z0f = floorf(zc), y0f = floorf(yc), x0f = floorf(xc);
    float wz = zc - z0f, wy = yc - y0f, wx = xc - x0f;
    float wz0 = 1.0f - wz, wy0 = 1.0f - wy, wx0 = 1.0f - wx;

    int z0 = (int)z0f, y0 = (int)y0f, x0 = (int)x0f;
    int z1 = z0 + 1, y1 = y0 + 1, x1 = x0 + 1;

    bool vz0 = (unsigned)z0 < (unsigned)D, vz1 = (unsigned)z1 < (unsigned)D;
    bool vy0 = (unsigned)y0 < (unsigned)H, vy1 = (unsigned)y1 < (unsigned)H;
    bool vx0 = (unsigned)x0 < (unsigned)W, vx1 = (unsigned)x1 < (unsigned)W;

    int z0c = min(max(z0, 0), D - 1), z1c = min(max(z1, 0), D - 1);
    int y0c = min(max(y0, 0), H - 1), y1c = min(max(y1, 0), H - 1);
    int x0c = min(max(x0, 0), W - 1), x1c = min(max(x1, 0), W - 1);

    float w000 = wz0 * wy0 * wx0 * (float)(vz0 && vy0 && vx0);
    float w001 = wz0 * wy0 * wx  * (float)(vz0 && vy0 && vx1);
    float w010 = wz0 * wy  * wx0 * (float)(vz0 && vy1 && vx0);
    float w011 = wz0 * wy  * wx  * (float)(vz0 && vy1 && vx1);
    float w100 = wz  * wy0 * wx0 * (float)(vz1 && vy0 && vx0);
    float w101 = wz  * wy0 * wx  * (float)(vz1 && vy0 && vx1);
    float w110 = wz  * wy  * wx0 * (float)(vz1 && vy1 && vx0);
    float w111 = wz  * wy  * wx  * (float)(vz1 && vy1 && vx1);

    int r00 = (z0c * H + y0c) * W;
    int r01 = (z0c * H + y1c) * W;
    int r10 = (z1c * H + y0c) * W;
    int r11 = (z1c * H + y1c) * W;

    const float4* sb = src_t + b * N;

    float4 v000 = sb[r00 + x0c], v001 = sb[r00 + x1c];
    float4 v010 = sb[r01 + x0c], v011 = sb[r01 + x1c];
    float4 v100 = sb[r10 + x0c], v101 = sb[r10 + x1c];
    float4 v110 = sb[r11 + x0c], v111 = sb[r11 + x1c];

    float ax, ay, az, aw;
    ax = w000 * v000.x; ay = w000 * v000.y; az = w000 * v000.z; aw = w000 * v000.w;
    ax = fmaf(w001, v001.x, ax); ay = fmaf(w001, v001.y, ay); az = fmaf(w001, v001.z, az); aw = fmaf(w001, v001.w, aw);
    ax = fmaf(w010, v010.x, ax); ay = fmaf(w010, v010.y, ay); az = fmaf(w010, v010.z, az); aw = fmaf(w010, v010.w, aw);
    ax = fmaf(w011, v011.x, ax); ay = fmaf(w011, v011.y, ay); az = fmaf(w011, v011.z, az); aw = fmaf(w011, v011.w, aw);
    ax = fmaf(w100, v100.x, ax); ay = fmaf(w100, v100.y, ay); az = fmaf(w100, v100.z, az); aw = fmaf(w100, v100.w, aw);
    ax = fmaf(w101, v101.x, ax); ay = fmaf(w101, v101.y, ay); az = fmaf(w101, v101.z, az); aw = fmaf(w101, v101.w, aw);
    ax = fmaf(w110, v110.x, ax); ay = fmaf(w110, v110.y, ay); az = fmaf(w110, v110.z, az); aw = fmaf(w110, v110.w, aw);
    ax = fmaf(w111, v111.x, ax); ay = fmaf(w111, v111.y, ay); az = fmaf(w111, v111.z, az); aw = fmaf(w111, v111.w, aw);

    float* ob = out + b * C * N + s;
    __builtin_nontemporal_store(ax, ob);
    __builtin_nontemporal_store(ay, ob + N);
    __builtin_nontemporal_store(az, ob + 2 * N);
    __builtin_nontemporal_store(aw, ob + 3 * N);
}

// ---------------------------------------------------------------------------
// Fallback (round-1 kernel) in case ws_size is too small for src_t.
// ---------------------------------------------------------------------------
__global__ __launch_bounds__(256) void warp3d_kernel(
    const float* __restrict__ src, const float* __restrict__ flow,
    float* __restrict__ out)
{
    int tid = blockIdx.x * blockDim.x + threadIdx.x;
    if (tid >= B * N) return;
    int b = (tid >= N) ? 1 : 0;
    int s = tid - b * N;
    int x = s % W;
    int t = s / W;
    int y = t % H;
    int z = t / H;

    const float* fl = flow + b * 3 * N + s;
    float zc = (float)z + fl[0];
    float yc = (float)y + fl[N];
    float xc = (float)x + fl[2 * N];

    float z0f = floorf(zc), y0f = floorf(yc), x0f = floorf(xc);
    float wz = zc - z0f, wy = yc - y0f, wx = xc - x0f;
    float wz0 = 1.0f - wz, wy0 = 1.0f - wy, wx0 = 1.0f - wx;

    int z0 = (int)z0f, y0 = (int)y0f, x0 = (int)x0f;
    int z1 = z0 + 1, y1 = y0 + 1, x1 = x0 + 1;

    bool vz0 = (unsigned)z0 < (unsigned)D, vz1 = (unsigned)z1 < (unsigned)D;
    bool vy0 = (unsigned)y0 < (unsigned)H, vy1 = (unsigned)y1 < (unsigned)H;
    bool vx0 = (unsigned)x0 < (unsigned)W, vx1 = (unsigned)x1 < (unsigned)W;

    int z0c = min(max(z0, 0), D - 1), z1c = min(max(z1, 0), D - 1);
    int y0c = min(max(y0, 0), H - 1), y1c = min(max(y1, 0), H - 1);
    int x0c = min(max(x0, 0), W - 1), x1c = min(max(x1, 0), W - 1);

    float w000 = wz0 * wy0 * wx0 * (float)(vz0 && vy0 && vx0);
    float w001 = wz0 * wy0 * wx  * (float)(vz0 && vy0 && vx1);
    float w010 = wz0 * wy  * wx0 * (float)(vz0 && vy1 && vx0);
    float w011 = wz0 * wy  * wx  * (float)(vz0 && vy1 && vx1);
    float w100 = wz  * wy0 * wx0 * (float)(vz1 && vy0 && vx0);
    float w101 = wz  * wy0 * wx  * (float)(vz1 && vy0 && vx1);
    float w110 = wz  * wy  * wx0 * (float)(vz1 && vy1 && vx0);
    float w111 = wz  * wy  * wx  * (float)(vz1 && vy1 && vx1);

    int r00 = (z0c * H + y0c) * W;
    int r01 = (z0c * H + y1c) * W;
    int r10 = (z1c * H + y0c) * W;
    int r11 = (z1c * H + y1c) * W;
    int i000 = r00 + x0c, i001 = r00 + x1c;
    int i010 = r01 + x0c, i011 = r01 + x1c;
    int i100 = r10 + x0c, i101 = r10 + x1c;
    int i110 = r11 + x0c, i111 = r11 + x1c;

    const float* sb = src + b * C * N;
    float* ob = out + b * C * N + s;

    #pragma unroll
    for (int c = 0; c < C; ++c) {
        const float* sp = sb + c * N;
        float v = w000 * sp[i000] + w001 * sp[i001]
                + w010 * sp[i010] + w011 * sp[i011]
                + w100 * sp[i100] + w101 * sp[i101]
                + w110 * sp[i110] + w111 * sp[i111];
        ob[c * N] = v;
    }
}

extern "C" void kernel_launch(void* const* d_in, const int* in_sizes, int n_in,
                              void* d_out, int out_size, void* d_ws, size_t ws_size,
                              hipStream_t stream) {
    const float* src  = (const float*)d_in[0];
    const float* flow = (const float*)d_in[1];
    float* out = (float*)d_out;

    int total = B * N;                       // 6,553,600
    int block = 256;
    int grid = (total + block - 1) / block;  // 25600, multiple of 8

    size_t need = (size_t)B * N * sizeof(float4);  // 104,857,600 bytes
    if (ws_size >= need) {
        float4* src_t = (float4*)d_ws;
        transpose_kernel<<<grid, block, 0, stream>>>(src, src_t);
        warp3d_t_kernel<<<grid, block, 0, stream>>>(src_t, flow, out);
    } else {
        warp3d_kernel<<<grid, block, 0, stream>>>(src, flow, out);
    }
}

// Round 3
// 161.998 us; speedup vs baseline: 2.9994x; 1.7024x over previous
//
#include <hip/hip_runtime.h>

// Problem constants (from reference setup_inputs)
constexpr int B = 2, C = 4, D = 128, H = 160, W = 160;
constexpr int N = D * H * W;          // 3,276,800 spatial positions per batch

typedef _Float16 h4 __attribute__((ext_vector_type(4)));
typedef _Float16 h8 __attribute__((ext_vector_type(8)));
typedef float    f2 __attribute__((ext_vector_type(2)));

// ---------------------------------------------------------------------------
// Pass 1: transpose+compress src [B,C,D,H,W] f32 -> src_h [B,D,H,W,C] fp16x4.
// 2 voxels per thread: 4x float2 plane reads -> one 16B write. Fully coalesced.
// ---------------------------------------------------------------------------
__global__ __launch_bounds__(256) void transpose_h_kernel(
    const float* __restrict__ src, h8* __restrict__ dst)
{
    int tid = blockIdx.x * blockDim.x + threadIdx.x;   // over B*N/2
    if (tid >= B * (N / 2)) return;
    int b = (tid >= (N / 2)) ? 1 : 0;                  // B == 2
    int s = (tid - b * (N / 2)) * 2;
    const float* sb = src + b * C * N + s;
    f2 c0 = *reinterpret_cast<const f2*>(sb);
    f2 c1 = *reinterpret_cast<const f2*>(sb + N);
    f2 c2 = *reinterpret_cast<const f2*>(sb + 2 * N);
    f2 c3 = *reinterpret_cast<const f2*>(sb + 3 * N);
    h8 o;
    o[0] = (_Float16)c0.x; o[1] = (_Float16)c1.x;
    o[2] = (_Float16)c2.x; o[3] = (_Float16)c3.x;
    o[4] = (_Float16)c0.y; o[5] = (_Float16)c1.y;
    o[6] = (_Float16)c2.y; o[7] = (_Float16)c3.y;
    dst[tid] = o;                                      // 16B aligned, coalesced
}

// ---------------------------------------------------------------------------
// Pass 2: trilinear warp from fp16x4-interleaved src_h.
// Per thread: 3 nt flow loads, FOUR 16B gathers (each covers BOTH x-corners of
// one (z,y) row since voxels are 8B), fp32 blend, 4 nt stores.
// ---------------------------------------------------------------------------
__global__ __launch_bounds__(256) void warp3d_h_kernel(
    const h4* __restrict__ src_h,      // [B, N] fp16x4
    const float* __restrict__ flow,    // [B, 3, N]
    float* __restrict__ out)           // [B, C, N]
{
    // bijective XCD swizzle: each XCD gets a contiguous z-slab of the grid
    int chunk = (int)gridDim.x >> 3;
    int swz = ((int)blockIdx.x & 7) * chunk + ((int)blockIdx.x >> 3);
    int tid = swz * (int)blockDim.x + (int)threadIdx.x;
    if (tid >= B * N) return;

    int b = (tid >= N) ? 1 : 0;
    int s = tid - b * N;
    int x = s % W;
    int t = s / W;
    int y = t % H;
    int z = t / H;

    const float* fl = flow + b * 3 * N + s;
    float zc = (float)z + __builtin_nontemporal_load(fl);
    float yc = (float)y + __builtin_nontemporal_load(fl + N);
    float xc = (float)x + __builtin_nontemporal_load(fl + 2 * N);

    float z0f = floorf(zc), y0f = floorf(yc), x0f = floorf(xc);
    float wz = zc - z0f, wy = yc - y0f, wx = xc - x0f;
    float wz0 = 1.0f - wz, wy0 = 1.0f - wy, wx0 = 1.0f - wx;

    int z0 = (int)z0f, y0 = (int)y0f, x0 = (int)x0f;
    int z1 = z0 + 1, y1 = y0 + 1, x1 = x0 + 1;

    bool vz0 = (unsigned)z0 < (unsigned)D, vz1 = (unsigned)z1 < (unsigned)D;
    bool vy0 = (unsigned)y0 < (unsigned)H, vy1 = (unsigned)y1 < (unsigned)H;
    bool vx0 = (unsigned)x0 < (unsigned)W, vx1 = (unsigned)x1 < (unsigned)W;

    int z0c = min(max(z0, 0), D - 1), z1c = min(max(z1, 0), D - 1);
    int y0c = min(max(y0, 0), H - 1), y1c = min(max(y1, 0), H - 1);

    // x base: one 16B load covers voxels xb and xb+1; select slots per corner.
    int xb = min(max(x0, 0), W - 2);
    int i0 = min(max(x0 - xb, 0), 1);   // slot of x0-corner (weight 0 if invalid)
    int i1 = min(max(x1 - xb, 0), 1);   // slot of x1-corner

    // per-corner weights (x0-corner, x1-corner) for each of the 4 rows
    float w000 = wz0 * wy0 * wx0 * (float)(vz0 && vy0 && vx0);
    float w001 = wz0 * wy0 * wx  * (float)(vz0 && vy0 && vx1);
    float w010 = wz0 * wy  * wx0 * (float)(vz0 && vy1 && vx0);
    float w011 = wz0 * wy  * wx  * (float)(vz0 && vy1 && vx1);
    float w100 = wz  * wy0 * wx0 * (float)(vz1 && vy0 && vx0);
    float w101 = wz  * wy0 * wx  * (float)(vz1 && vy0 && vx1);
    float w110 = wz  * wy  * wx0 * (float)(vz1 && vy1 && vx0);
    float w111 = wz  * wy  * wx  * (float)(vz1 && vy1 && vx1);

    int r00 = (z0c * H + y0c) * W + xb;
    int r01 = (z0c * H + y1c) * W + xb;
    int r10 = (z1c * H + y0c) * W + xb;
    int r11 = (z1c * H + y1c) * W + xb;

    const h4* sb = src_h + (size_t)b * N;

    h8 p00, p01, p10, p11;
    __builtin_memcpy(&p00, sb + r00, 16);   // 8B-aligned 16B load
    __builtin_memcpy(&p01, sb + r01, 16);
    __builtin_memcpy(&p10, sb + r10, 16);
    __builtin_memcpy(&p11, sb + r11, 16);

    float ax = 0.f, ay = 0.f, az = 0.f, aw = 0.f;

    #define BLEND(P, WA, WB)                                            \
    {                                                                   \
        h4 lo = { P[0], P[1], P[2], P[3] };                             \
        h4 hi = { P[4], P[5], P[6], P[7] };                             \
        h4 vA = i0 ? hi : lo;                                           \
        h4 vB = i1 ? hi : lo;                                           \
        ax = fmaf(WA, (float)vA[0], ax); ax = fmaf(WB, (float)vB[0], ax);\
        ay = fmaf(WA, (float)vA[1], ay); ay = fmaf(WB, (float)vB[1], ay);\
        az = fmaf(WA, (float)vA[2], az); az = fmaf(WB, (float)vB[2], az);\
        aw = fmaf(WA, (float)vA[3], aw); aw = fmaf(WB, (float)vB[3], aw);\
    }

    BLEND(p00, w000, w001);
    BLEND(p01, w010, w011);
    BLEND(p10, w100, w101);
    BLEND(p11, w110, w111);
    #undef BLEND

    float* ob = out + b * C * N + s;
    __builtin_nontemporal_store(ax, ob);
    __builtin_nontemporal_store(ay, ob + N);
    __builtin_nontemporal_store(az, ob + 2 * N);
    __builtin_nontemporal_store(aw, ob + 3 * N);
}

// ---------------------------------------------------------------------------
// Fallback (round-1 kernel) in case ws_size is too small for src_h.
// ---------------------------------------------------------------------------
__global__ __launch_bounds__(256) void warp3d_kernel(
    const float* __restrict__ src, const float* __restrict__ flow,
    float* __restrict__ out)
{
    int tid = blockIdx.x * blockDim.x + threadIdx.x;
    if (tid >= B * N) return;
    int b = (tid >= N) ? 1 : 0;
    int s = tid - b * N;
    int x = s % W;
    int t = s / W;
    int y = t % H;
    int z = t / H;

    const float* fl = flow + b * 3 * N + s;
    float zc = (float)z + fl[0];
    float yc = (float)y + fl[N];
    float xc = (float)x + fl[2 * N];

    float z0f = floorf(zc), y0f = floorf(yc), x0f = floorf(xc);
    float wz = zc - z0f, wy = yc - y0f, wx = xc - x0f;
    float wz0 = 1.0f - wz, wy0 = 1.0f - wy, wx0 = 1.0f - wx;

    int z0 = (int)z0f, y0 = (int)y0f, x0 = (int)x0f;
    int z1 = z0 + 1, y1 = y0 + 1, x1 = x0 + 1;

    bool vz0 = (unsigned)z0 < (unsigned)D, vz1 = (unsigned)z1 < (unsigned)D;
    bool vy0 = (unsigned)y0 < (unsigned)H, vy1 = (unsigned)y1 < (unsigned)H;
    bool vx0 = (unsigned)x0 < (unsigned)W, vx1 = (unsigned)x1 < (unsigned)W;

    int z0c = min(max(z0, 0), D - 1), z1c = min(max(z1, 0), D - 1);
    int y0c = min(max(y0, 0), H - 1), y1c = min(max(y1, 0), H - 1);
    int x0c = min(max(x0, 0), W - 1), x1c = min(max(x1, 0), W - 1);

    float w000 = wz0 * wy0 * wx0 * (float)(vz0 && vy0 && vx0);
    float w001 = wz0 * wy0 * wx  * (float)(vz0 && vy0 && vx1);
    float w010 = wz0 * wy  * wx0 * (float)(vz0 && vy1 && vx0);
    float w011 = wz0 * wy  * wx  * (float)(vz0 && vy1 && vx1);
    float w100 = wz  * wy0 * wx0 * (float)(vz1 && vy0 && vx0);
    float w101 = wz  * wy0 * wx  * (float)(vz1 && vy0 && vx1);
    float w110 = wz  * wy  * wx0 * (float)(vz1 && vy1 && vx0);
    float w111 = wz  * wy  * wx  * (float)(vz1 && vy1 && vx1);

    int r00 = (z0c * H + y0c) * W;
    int r01 = (z0c * H + y1c) * W;
    int r10 = (z1c * H + y0c) * W;
    int r11 = (z1c * H + y1c) * W;
    int i000 = r00 + x0c, i001 = r00 + x1c;
    int i010 = r01 + x0c, i011 = r01 + x1c;
    int i100 = r10 + x0c, i101 = r10 + x1c;
    int i110 = r11 + x0c, i111 = r11 + x1c;

    const float* sb = src + b * C * N;
    float* ob = out + b * C * N + s;

    #pragma unroll
    for (int c = 0; c < C; ++c) {
        const float* sp = sb + c * N;
        float v = w000 * sp[i000] + w001 * sp[i001]
                + w010 * sp[i010] + w011 * sp[i011]
                + w100 * sp[i100] + w101 * sp[i101]
                + w110 * sp[i110] + w111 * sp[i111];
        ob[c * N] = v;
    }
}

extern "C" void kernel_launch(void* const* d_in, const int* in_sizes, int n_in,
                              void* d_out, int out_size, void* d_ws, size_t ws_size,
                              hipStream_t stream) {
    const float* src  = (const float*)d_in[0];
    const float* flow = (const float*)d_in[1];
    float* out = (float*)d_out;

    int total = B * N;                        // 6,553,600
    int block = 256;
    int grid = (total + block - 1) / block;   // 25600, multiple of 8

    size_t need = (size_t)B * N * sizeof(h4); // 52,428,800 bytes
    if (ws_size >= need) {
        h8* src_h = (h8*)d_ws;
        int tgrid = (B * (N / 2) + block - 1) / block;   // 12800
        transpose_h_kernel<<<tgrid, block, 0, stream>>>(src, src_h);
        warp3d_h_kernel<<<grid, block, 0, stream>>>((const h4*)d_ws, flow, out);
    } else {
        warp3d_kernel<<<grid, block, 0, stream>>>(src, flow, out);
    }
}